// Round 16
// baseline (941.297 us; speedup 1.0000x reference)
//
#include <hip/hip_runtime.h>
#include <hip/hip_bf16.h>

namespace {
constexpr int S = 2048;
constexpr int D = 64;
constexpr float QSCALE = 0.18033688011112042f;  // (1/sqrt(64)) * log2(e)

using f32x4 = __attribute__((ext_vector_type(4))) float;
using bf16x8 = __attribute__((ext_vector_type(8))) short;
using s16x4 = __attribute__((ext_vector_type(4))) short;  // NT-store-compatible

__device__ __forceinline__ short f2bf(float f) {
  return __builtin_bit_cast(short, __float2bfloat16(f));  // native RNE cvt
}
__device__ __forceinline__ float bf2f(unsigned short s) {
  return __builtin_bit_cast(float, (unsigned)s << 16);
}
#if __has_builtin(__builtin_amdgcn_exp2f)
__device__ __forceinline__ float exp2_fast(float x) { return __builtin_amdgcn_exp2f(x); }
#else
__device__ __forceinline__ float exp2_fast(float x) { return exp2f(x); }
#endif

__device__ __forceinline__ void bar_lds() {  // lgkm-only barrier: vmem prefetch stays in flight
  asm volatile("s_waitcnt lgkmcnt(0)" ::: "memory");
  __builtin_amdgcn_s_barrier();
}
}  // namespace

// One block = (bh, 64 q-rows).
//   1) zero-fill a[:, NT*64:) (NT stores, drain under compute)
//   2) loop A: QK+exp -> l, PV -> O_unnorm, AND stream p~ (bf16, NT) into the
//      LOW HALF of each a-row's own allocation (stores flow during A!)
//   3) O write (normalized)
//   4) expand: in-place per-wave sweep high->low turning bf16 p~ into fp32
//      p~*rl  (pure stream, no MFMA/LDS/barriers)
// All a-region accesses are nontemporal -> L1 never caches them (replay-safe).
// 40KB LDS -> 4 blocks/CU.
__global__ __launch_bounds__(256, 4) void attn_fused(const float* __restrict__ qg,
                                                     const float* __restrict__ kg,
                                                     const float* __restrict__ vg,
                                                     float* __restrict__ outg) {
  __shared__ short kbuf[2][64 * 64];   // K[j][d] bf16, XOR-swizzled, dbuf
  __shared__ short vbuf[2][64 * 64];   // V^T[d][j] bf16, XOR-swizzled, dbuf
  __shared__ short pscr[4][16 * 64];   // per-wave p~ redistribution scratch

  const int tid = threadIdx.x;
  const int w = tid >> 6, lane = tid & 63, lg = lane >> 4, lr = lane & 15;

  // XCD-chunked block map + long/short qt interleave for co-resident balance
  const int u = blockIdx.x;
  const int logical = (u & 7) * 256 + (u >> 3);  // 2048 % 8 == 0
  const int bh = logical >> 5;
  const int uu = logical & 31;
  const int qt = (uu & 1) ? (31 - (uu >> 1)) : (uu >> 1);
  const int qrow0 = qt * 64;
  const int NT = qt + 1;

  const size_t bh_off = (size_t)bh * S * D;
  float* const og = outg;
  float* const a_base = outg + (size_t)64 * S * D + (size_t)bh * S * S;
  const int asw = (lr & 7) << 3;

  const int igl = qrow0 + w * 16 + lr;  // this lane's q-row (QK col i / p row)

  const int krow = tid >> 2, kc = (tid & 3) * 16;
  const int kswz = (krow & 7) << 3;
  const int vj = tid & 63, vd0 = (tid >> 6) * 16;

  f32x4 ka[4], va[4];

#define LOAD_K(kt_) do { const float* kp_ = kg + bh_off + (size_t)((kt_) * 64 + krow) * D + kc; \
    ka[0] = *(const f32x4*)(kp_);     ka[1] = *(const f32x4*)(kp_ + 4);                         \
    ka[2] = *(const f32x4*)(kp_ + 8); ka[3] = *(const f32x4*)(kp_ + 12); } while (0)
#define LOAD_V(kt_) do { const float* vp_ = vg + bh_off + (size_t)((kt_) * 64 + vj) * D + vd0;  \
    va[0] = *(const f32x4*)(vp_);     va[1] = *(const f32x4*)(vp_ + 4);                         \
    va[2] = *(const f32x4*)(vp_ + 8); va[3] = *(const f32x4*)(vp_ + 12); } while (0)
#define STAGE_K(buf_) do { bf16x8 kb_;                                                           \
    _Pragma("unroll") for (int e = 0; e < 4; ++e) { kb_[e] = f2bf(ka[0][e]); kb_[e+4] = f2bf(ka[1][e]); } \
    *(bf16x8*)(&kbuf[buf_][(krow * 64 + kc) ^ kswz]) = kb_;                                      \
    _Pragma("unroll") for (int e = 0; e < 4; ++e) { kb_[e] = f2bf(ka[2][e]); kb_[e+4] = f2bf(ka[3][e]); } \
    *(bf16x8*)(&kbuf[buf_][(krow * 64 + kc + 8) ^ kswz]) = kb_; } while (0)
#define STAGE_V(buf_) do {                                                                       \
    _Pragma("unroll") for (int i = 0; i < 4; ++i)                                                \
    _Pragma("unroll") for (int e = 0; e < 4; ++e) {                                              \
      const int d_ = vd0 + i * 4 + e;                                                            \
      vbuf[buf_][(d_ * 64 + vj) ^ ((d_ & 7) << 3)] = f2bf(va[i][e]); } } while (0)

  // ---- issue tile-0 K/V loads BEFORE the zero-fill store burst (latency hides) ----
  LOAD_K(0);
  LOAD_V(0);

  // ---- zero tiles (j >= NT*64) FIRST: fire-and-forget NT stores ----
  float* const arow = a_base + (size_t)igl * S;
  {
    const f32x4 z = {0.f, 0.f, 0.f, 0.f};
    for (int zt = NT; zt < S / 64; ++zt) {
#pragma unroll
      for (int jb = 0; jb < 4; ++jb)
        __builtin_nontemporal_store(z, (f32x4*)(arow + zt * 64 + jb * 16 + lg * 4));
    }
  }

  // ---- Q B-fragment (col i = lane's row, k = d), QSCALE folded ----
  bf16x8 qf[2];
#pragma unroll
  for (int kh = 0; kh < 2; ++kh) {
    const float* qp = qg + bh_off + (size_t)igl * D + kh * 32 + lg * 8;
    f32x4 x0 = *(const f32x4*)(qp);
    f32x4 x1 = *(const f32x4*)(qp + 4);
    bf16x8 f;
#pragma unroll
    for (int e = 0; e < 4; ++e) {
      f[e] = f2bf(x0[e] * QSCALE);
      f[e + 4] = f2bf(x1[e] * QSCALE);
    }
    qf[kh] = f;
  }

  // ====== loop A: l + O(unnormalized) + p~ streamed into a's low half ======
  STAGE_K(0);
  STAGE_V(0);
  bar_lds();

  float l_acc = 0.f;
  f32x4 oacc[4];
#pragma unroll
  for (int dg = 0; dg < 4; ++dg) oacc[dg] = (f32x4){0.f, 0.f, 0.f, 0.f};

  unsigned short* const prow = (unsigned short*)arow;  // bf16 p~ row, in-place

  for (int kt = 0; kt < NT; ++kt) {
    const int cur = kt & 1;
    if (kt + 1 < NT) {  // prefetch next K/V tiles into regs
      LOAD_K(kt + 1);
      LOAD_V(kt + 1);
    }

    // QK^T: D[j][i], lane col i = lr, rows j = jb*16 + lg*4 + r
    f32x4 sacc[4];
#pragma unroll
    for (int jb = 0; jb < 4; ++jb) sacc[jb] = (f32x4){0.f, 0.f, 0.f, 0.f};
#pragma unroll
    for (int kh = 0; kh < 2; ++kh) {
#pragma unroll
      for (int jb = 0; jb < 4; ++jb) {
        bf16x8 kf = *(const bf16x8*)(&kbuf[cur][((jb * 16 + lr) * 64 + kh * 32 + lg * 8) ^ asw]);
        sacc[jb] = __builtin_amdgcn_mfma_f32_16x16x32_bf16(kf, qf[kh], sacc[jb], 0, 0, 0);
      }
    }

    // p~ = exp2(s) (masked on diagonal tile); accumulate l; pscr for PV;
    // AND stream p~ bf16 to global (a's low half) - stores flow during A
    const bool diag = (kt == NT - 1);
#pragma unroll
    for (int jb = 0; jb < 4; ++jb) {
      s16x4 ps;
#pragma unroll
      for (int r = 0; r < 4; ++r) {
        const int jgl = kt * 64 + jb * 16 + lg * 4 + r;
        float pt = exp2_fast(sacc[jb][r]);
        if (diag && jgl > igl) pt = 0.f;
        l_acc += pt;
        ps[r] = f2bf(pt);
      }
      *(s16x4*)(&pscr[w][(lr * 64 + jb * 16 + lg * 4) ^ asw]) = ps;
      __builtin_nontemporal_store(ps, (s16x4*)(prow + kt * 64 + jb * 16 + lg * 4));
    }

    // PV: O[i][d] += p~ V (pscr same-wave)
#pragma unroll
    for (int ks = 0; ks < 2; ++ks) {
      bf16x8 pa = *(const bf16x8*)(&pscr[w][(lr * 64 + ks * 32 + lg * 8) ^ asw]);
#pragma unroll
      for (int dg = 0; dg < 4; ++dg) {
        bf16x8 vb = *(const bf16x8*)(&vbuf[cur][((dg * 16 + lr) * 64 + ks * 32 + lg * 8) ^ asw]);
        oacc[dg] = __builtin_amdgcn_mfma_f32_16x16x32_bf16(pa, vb, oacc[dg], 0, 0, 0);
      }
    }

    if (kt + 1 < NT) {  // stage next tiles into the other buffers
      STAGE_K(cur ^ 1);
      STAGE_V(cur ^ 1);
    }
    bar_lds();
  }

  // ---- rl: reduce partials across lg; lane then holds rl for its row igl ----
  l_acc += __shfl_xor(l_acc, 16, 64);
  l_acc += __shfl_xor(l_acc, 32, 64);
  const float rlA = 1.f / l_acc;

  // Publish per-wave rl table (rows w*16+0..15); also used by the expand phase
  float* const rlv = (float*)(&pscr[w][0]);
  if (lane < 16) rlv[lr] = rlA;
  asm volatile("s_waitcnt lgkmcnt(0)" ::: "memory");  // same-wave write->read

  // ---- O write: lane holds O[i=w*16+lg*4+r][d=dg*16+lr] ----
#pragma unroll
  for (int dg = 0; dg < 4; ++dg) {
#pragma unroll
    for (int r = 0; r < 4; ++r) {
      const int il = qrow0 + w * 16 + lg * 4 + r;
      og[bh_off + (size_t)il * D + dg * 16 + lr] = oacc[dg][r] * rlv[lg * 4 + r];
    }
  }

  // ====== expand: in-place bf16 p~ -> fp32 p~*rl, per wave over its 16 rows ======
  // High->low column sweep: write [4c,4c+256) never clobbers a later read
  // [2c',2c'+128) since c' <= c-64. Lowest chunk is load-then-store ordered.
  asm volatile("s_waitcnt vmcnt(0)" ::: "memory");  // own p~ stores at L2
  for (int rr = 0; rr < 16; ++rr) {
    const int row = qrow0 + w * 16 + rr;
    const float rls = rlv[rr];
    float* const aro = a_base + (size_t)row * S;
    const unsigned short* const pro = (const unsigned short*)aro;
    for (int cc = NT * 64 - 64; cc >= 0; cc -= 64) {
      unsigned short pv = __builtin_nontemporal_load(pro + cc + lane);
      float av = bf2f(pv) * rls;
      __builtin_nontemporal_store(av, aro + cc + lane);
    }
  }

#undef LOAD_K
#undef LOAD_V
#undef STAGE_K
#undef STAGE_V
}

extern "C" void kernel_launch(void* const* d_in, const int* in_sizes, int n_in,
                              void* d_out, int out_size, void* d_ws, size_t ws_size,
                              hipStream_t stream) {
  const float* q = (const float*)d_in[0];
  const float* k = (const float*)d_in[1];
  const float* v = (const float*)d_in[2];
  float* out = (float*)d_out;
  attn_fused<<<dim3(2048), dim3(256), 0, stream>>>(q, k, v, out);
}

// Round 17
// 348.853 us; speedup vs baseline: 2.6983x; 2.6983x over previous
//
#include <hip/hip_runtime.h>
#include <hip/hip_bf16.h>

namespace {
constexpr int S = 2048;
constexpr int D = 64;
constexpr float QSCALE = 0.18033688011112042f;  // (1/sqrt(64)) * log2(e)

using f32x4 = __attribute__((ext_vector_type(4))) float;
using bf16x8 = __attribute__((ext_vector_type(8))) short;

__device__ __forceinline__ short f2bf(float f) {
  return __builtin_bit_cast(short, __float2bfloat16(f));  // native RNE cvt
}
#if __has_builtin(__builtin_amdgcn_exp2f)
__device__ __forceinline__ float exp2_fast(float x) { return __builtin_amdgcn_exp2f(x); }
#else
__device__ __forceinline__ float exp2_fast(float x) { return exp2f(x); }
#endif

__device__ __forceinline__ void bar_lds() {  // lgkm-only barrier: vmem prefetch stays in flight
  asm volatile("s_waitcnt lgkmcnt(0)" ::: "memory");
  __builtin_amdgcn_s_barrier();
}
}  // namespace

// Round-10 best-known-good (348 us), reverted after rounds 11-16 refuted all
// further structural theories.
// One block = (bh, 64 q-rows). Zero-fill FIRST (stores overlap everyone's loop A),
// then loop A: QK+exp-sum+PV; then loop B: QK recompute -> normalized a stream.
// 40KB LDS -> 4 blocks/CU.
__global__ __launch_bounds__(256, 4) void attn_fused(const float* __restrict__ qg,
                                                     const float* __restrict__ kg,
                                                     const float* __restrict__ vg,
                                                     float* __restrict__ outg) {
  __shared__ short kbuf[2][64 * 64];   // K[j][d] bf16, XOR-swizzled, dbuf
  __shared__ short vbuf[2][64 * 64];   // V^T[d][j] bf16, XOR-swizzled, dbuf
  __shared__ short pscr[4][16 * 64];   // per-wave p~ redistribution scratch

  const int tid = threadIdx.x;
  const int w = tid >> 6, lane = tid & 63, lg = lane >> 4, lr = lane & 15;

  // XCD-chunked block map + long/short qt interleave for co-resident balance
  const int u = blockIdx.x;
  const int logical = (u & 7) * 256 + (u >> 3);  // 2048 % 8 == 0
  const int bh = logical >> 5;
  const int uu = logical & 31;
  const int qt = (uu & 1) ? (31 - (uu >> 1)) : (uu >> 1);
  const int qrow0 = qt * 64;
  const int NT = qt + 1;

  const size_t bh_off = (size_t)bh * S * D;
  float* const og = outg;
  float* const a_base = outg + (size_t)64 * S * D + (size_t)bh * S * S;
  const int asw = (lr & 7) << 3;

  const int igl = qrow0 + w * 16 + lr;  // this lane's q-row (QK col i / p row)

  // ---- zero tiles (j >= NT*64) FIRST: fire-and-forget NT stores that the
  // write pipe drains while this block (and all others) runs loop A ----
  {
    float* const arow = a_base + (size_t)igl * S;
    const f32x4 z = {0.f, 0.f, 0.f, 0.f};
    for (int zt = NT; zt < S / 64; ++zt) {
#pragma unroll
      for (int jb = 0; jb < 4; ++jb) {
        __builtin_nontemporal_store(z, (f32x4*)(arow + zt * 64 + jb * 16 + lg * 4));
      }
    }
  }

  // ---- Q B-fragment (col i = lr-row of this wave, k = d), QSCALE folded ----
  bf16x8 qf[2];
#pragma unroll
  for (int kh = 0; kh < 2; ++kh) {
    const float* qp = qg + bh_off + (size_t)igl * D + kh * 32 + lg * 8;
    f32x4 x0 = *(const f32x4*)(qp);
    f32x4 x1 = *(const f32x4*)(qp + 4);
    bf16x8 f;
#pragma unroll
    for (int e = 0; e < 4; ++e) {
      f[e] = f2bf(x0[e] * QSCALE);
      f[e + 4] = f2bf(x1[e] * QSCALE);
    }
    qf[kh] = f;
  }

  const int krow = tid >> 2, kc = (tid & 3) * 16;
  const int kswz = (krow & 7) << 3;
  const int vj = tid & 63, vd0 = (tid >> 6) * 16;

  // =========================== loop A: l + O(unnormalized) ===========================
  f32x4 ka[4], va[4];
  {
    const float* kp = kg + bh_off + (size_t)krow * D + kc;
#pragma unroll
    for (int i = 0; i < 4; ++i) ka[i] = *(const f32x4*)(kp + i * 4);
    const float* vp = vg + bh_off + (size_t)vj * D + vd0;
#pragma unroll
    for (int i = 0; i < 4; ++i) va[i] = *(const f32x4*)(vp + i * 4);
  }
  {  // stage tile 0
    bf16x8 kb;
#pragma unroll
    for (int e = 0; e < 4; ++e) { kb[e] = f2bf(ka[0][e]); kb[e + 4] = f2bf(ka[1][e]); }
    *(bf16x8*)(&kbuf[0][(krow * 64 + kc) ^ kswz]) = kb;
#pragma unroll
    for (int e = 0; e < 4; ++e) { kb[e] = f2bf(ka[2][e]); kb[e + 4] = f2bf(ka[3][e]); }
    *(bf16x8*)(&kbuf[0][(krow * 64 + kc + 8) ^ kswz]) = kb;
#pragma unroll
    for (int i = 0; i < 4; ++i)
#pragma unroll
      for (int e = 0; e < 4; ++e) {
        const int d = vd0 + i * 4 + e;
        vbuf[0][(d * 64 + vj) ^ ((d & 7) << 3)] = f2bf(va[i][e]);
      }
  }
  bar_lds();

  float l_acc = 0.f;
  f32x4 oacc[4];
#pragma unroll
  for (int dg = 0; dg < 4; ++dg) oacc[dg] = (f32x4){0.f, 0.f, 0.f, 0.f};

  for (int kt = 0; kt < NT; ++kt) {
    const int cur = kt & 1;
    if (kt + 1 < NT) {  // prefetch next K/V tiles into regs
      const float* kp = kg + bh_off + (size_t)((kt + 1) * 64 + krow) * D + kc;
#pragma unroll
      for (int i = 0; i < 4; ++i) ka[i] = *(const f32x4*)(kp + i * 4);
      const float* vp = vg + bh_off + (size_t)((kt + 1) * 64 + vj) * D + vd0;
#pragma unroll
      for (int i = 0; i < 4; ++i) va[i] = *(const f32x4*)(vp + i * 4);
    }

    // QK^T: D[j][i], lane col i = lr, rows j = jb*16 + lg*4 + r
    f32x4 sacc[4];
#pragma unroll
    for (int jb = 0; jb < 4; ++jb) sacc[jb] = (f32x4){0.f, 0.f, 0.f, 0.f};
#pragma unroll
    for (int kh = 0; kh < 2; ++kh) {
#pragma unroll
      for (int jb = 0; jb < 4; ++jb) {
        bf16x8 kf = *(const bf16x8*)(&kbuf[cur][((jb * 16 + lr) * 64 + kh * 32 + lg * 8) ^ asw]);
        sacc[jb] = __builtin_amdgcn_mfma_f32_16x16x32_bf16(kf, qf[kh], sacc[jb], 0, 0, 0);
      }
    }

    // p~ = exp2(s) (masked on diagonal tile); accumulate l; pscr for PV
    const bool diag = (kt == NT - 1);
#pragma unroll
    for (int jb = 0; jb < 4; ++jb) {
      short4 ps;
#pragma unroll
      for (int r = 0; r < 4; ++r) {
        const int jgl = kt * 64 + jb * 16 + lg * 4 + r;
        float pt = exp2_fast(sacc[jb][r]);
        if (diag && jgl > igl) pt = 0.f;
        l_acc += pt;
        ((short*)&ps)[r] = f2bf(pt);
      }
      *(short4*)(&pscr[w][(lr * 64 + jb * 16 + lg * 4) ^ asw]) = ps;
    }

    // PV: O[i][d] += p~ V (pscr same-wave)
#pragma unroll
    for (int ks = 0; ks < 2; ++ks) {
      bf16x8 pa = *(const bf16x8*)(&pscr[w][(lr * 64 + ks * 32 + lg * 8) ^ asw]);
#pragma unroll
      for (int dg = 0; dg < 4; ++dg) {
        bf16x8 vb = *(const bf16x8*)(&vbuf[cur][((dg * 16 + lr) * 64 + ks * 32 + lg * 8) ^ asw]);
        oacc[dg] = __builtin_amdgcn_mfma_f32_16x16x32_bf16(pa, vb, oacc[dg], 0, 0, 0);
      }
    }

    if (kt + 1 < NT) {  // stage next tile into the other buffers
      bf16x8 kb;
#pragma unroll
      for (int e = 0; e < 4; ++e) { kb[e] = f2bf(ka[0][e]); kb[e + 4] = f2bf(ka[1][e]); }
      *(bf16x8*)(&kbuf[cur ^ 1][(krow * 64 + kc) ^ kswz]) = kb;
#pragma unroll
      for (int e = 0; e < 4; ++e) { kb[e] = f2bf(ka[2][e]); kb[e + 4] = f2bf(ka[3][e]); }
      *(bf16x8*)(&kbuf[cur ^ 1][(krow * 64 + kc + 8) ^ kswz]) = kb;
#pragma unroll
      for (int i = 0; i < 4; ++i)
#pragma unroll
        for (int e = 0; e < 4; ++e) {
          const int d = vd0 + i * 4 + e;
          vbuf[cur ^ 1][(d * 64 + vj) ^ ((d & 7) << 3)] = f2bf(va[i][e]);
        }
    }
    bar_lds();
  }

  // ---- rl: reduce partials across lg; lane then holds rl for its row igl ----
  l_acc += __shfl_xor(l_acc, 16, 64);
  l_acc += __shfl_xor(l_acc, 32, 64);
  const float rlA = 1.f / l_acc;

  // O rescale needs rl at rows w*16+lg*4+r: bounce via per-wave pscr region
  {
    float* const rlv = (float*)(&pscr[w][0]);
    if (lane < 16) rlv[lr] = rlA;
    asm volatile("s_waitcnt lgkmcnt(0)" ::: "memory");  // same-wave write->read
#pragma unroll
    for (int dg = 0; dg < 4; ++dg) {
#pragma unroll
      for (int r = 0; r < 4; ++r) {
        const int il = qrow0 + w * 16 + lg * 4 + r;
        og[bh_off + (size_t)il * D + dg * 16 + lr] = oacc[dg][r] * rlv[lg * 4 + r];
      }
    }
  }

  // =========================== loop B: stream normalized a ===========================
  float* const arow = a_base + (size_t)igl * S;
  {
    const float* kp = kg + bh_off + (size_t)krow * D + kc;
#pragma unroll
    for (int i = 0; i < 4; ++i) ka[i] = *(const f32x4*)(kp + i * 4);
  }
  {  // stage tile 0 (A-loop reads of kbuf[0] finished at A's last barrier)
    bf16x8 kb;
#pragma unroll
    for (int e = 0; e < 4; ++e) { kb[e] = f2bf(ka[0][e]); kb[e + 4] = f2bf(ka[1][e]); }
    *(bf16x8*)(&kbuf[0][(krow * 64 + kc) ^ kswz]) = kb;
#pragma unroll
    for (int e = 0; e < 4; ++e) { kb[e] = f2bf(ka[2][e]); kb[e + 4] = f2bf(ka[3][e]); }
    *(bf16x8*)(&kbuf[0][(krow * 64 + kc + 8) ^ kswz]) = kb;
  }
  bar_lds();

  for (int kt = 0; kt < NT; ++kt) {
    const int cur = kt & 1;
    if (kt + 1 < NT) {  // prefetch next K tile (issued BEFORE this tile's stores)
      const float* kp = kg + bh_off + (size_t)((kt + 1) * 64 + krow) * D + kc;
#pragma unroll
      for (int i = 0; i < 4; ++i) ka[i] = *(const f32x4*)(kp + i * 4);
    }

    f32x4 sacc[4];
#pragma unroll
    for (int jb = 0; jb < 4; ++jb) sacc[jb] = (f32x4){0.f, 0.f, 0.f, 0.f};
#pragma unroll
    for (int kh = 0; kh < 2; ++kh) {
#pragma unroll
      for (int jb = 0; jb < 4; ++jb) {
        bf16x8 kf = *(const bf16x8*)(&kbuf[cur][((jb * 16 + lr) * 64 + kh * 32 + lg * 8) ^ asw]);
        sacc[jb] = __builtin_amdgcn_mfma_f32_16x16x32_bf16(kf, qf[kh], sacc[jb], 0, 0, 0);
      }
    }

    const bool diag = (kt == NT - 1);
#pragma unroll
    for (int jb = 0; jb < 4; ++jb) {
      f32x4 av;
#pragma unroll
      for (int r = 0; r < 4; ++r) {
        const int jgl = kt * 64 + jb * 16 + lg * 4 + r;
        float pt = exp2_fast(sacc[jb][r]);
        if (diag && jgl > igl) pt = 0.f;
        av[r] = pt * rlA;
      }
      __builtin_nontemporal_store(av, (f32x4*)(arow + kt * 64 + jb * 16 + lg * 4));
    }

    if (kt + 1 < NT) {
      bf16x8 kb;
#pragma unroll
      for (int e = 0; e < 4; ++e) { kb[e] = f2bf(ka[0][e]); kb[e + 4] = f2bf(ka[1][e]); }
      *(bf16x8*)(&kbuf[cur ^ 1][(krow * 64 + kc) ^ kswz]) = kb;
#pragma unroll
      for (int e = 0; e < 4; ++e) { kb[e] = f2bf(ka[2][e]); kb[e + 4] = f2bf(ka[3][e]); }
      *(bf16x8*)(&kbuf[cur ^ 1][(krow * 64 + kc + 8) ^ kswz]) = kb;
    }
    bar_lds();
  }
}

extern "C" void kernel_launch(void* const* d_in, const int* in_sizes, int n_in,
                              void* d_out, int out_size, void* d_ws, size_t ws_size,
                              hipStream_t stream) {
  const float* q = (const float*)d_in[0];
  const float* k = (const float*)d_in[1];
  const float* v = (const float*)d_in[2];
  float* out = (float*)d_out;
  attn_fused<<<dim3(2048), dim3(256), 0, stream>>>(q, k, v, out);
}

// Round 18
// 298.624 us; speedup vs baseline: 3.1521x; 1.1682x over previous
//
#include <hip/hip_runtime.h>
#include <hip/hip_bf16.h>

namespace {
constexpr int S = 2048;
constexpr int D = 64;
constexpr float QSCALE = 0.18033688011112042f;  // (1/sqrt(64)) * log2(e)

using f32x4 = __attribute__((ext_vector_type(4))) float;
using bf16x8 = __attribute__((ext_vector_type(8))) short;

__device__ __forceinline__ short f2bf(float f) {
  return __builtin_bit_cast(short, __float2bfloat16(f));  // native RNE cvt
}
#if __has_builtin(__builtin_amdgcn_exp2f)
__device__ __forceinline__ float exp2_fast(float x) { return __builtin_amdgcn_exp2f(x); }
#else
__device__ __forceinline__ float exp2_fast(float x) { return exp2f(x); }
#endif

__device__ __forceinline__ void bar_lds() {  // lgkm-only barrier: vmem prefetch stays in flight
  asm volatile("s_waitcnt lgkmcnt(0)" ::: "memory");
  __builtin_amdgcn_s_barrier();
}
}  // namespace

// r10 best-known-good (348 us) + ONE change: zero-fill stores regrouped so each
// instruction writes 256B-contiguous runs (2 full 128B lines) per row instead of
// scattered 64B segments. Single-variable test of NT partial-line write cost.
// 40KB LDS -> 4 blocks/CU.
__global__ __launch_bounds__(256, 4) void attn_fused(const float* __restrict__ qg,
                                                     const float* __restrict__ kg,
                                                     const float* __restrict__ vg,
                                                     float* __restrict__ outg) {
  __shared__ short kbuf[2][64 * 64];   // K[j][d] bf16, XOR-swizzled, dbuf
  __shared__ short vbuf[2][64 * 64];   // V^T[d][j] bf16, XOR-swizzled, dbuf
  __shared__ short pscr[4][16 * 64];   // per-wave p~ redistribution scratch

  const int tid = threadIdx.x;
  const int w = tid >> 6, lane = tid & 63, lg = lane >> 4, lr = lane & 15;

  // XCD-chunked block map + long/short qt interleave for co-resident balance
  const int u = blockIdx.x;
  const int logical = (u & 7) * 256 + (u >> 3);  // 2048 % 8 == 0
  const int bh = logical >> 5;
  const int uu = logical & 31;
  const int qt = (uu & 1) ? (31 - (uu >> 1)) : (uu >> 1);
  const int qrow0 = qt * 64;
  const int NT = qt + 1;

  const size_t bh_off = (size_t)bh * S * D;
  float* const og = outg;
  float* const a_base = outg + (size_t)64 * S * D + (size_t)bh * S * S;
  const int asw = (lr & 7) << 3;

  const int igl = qrow0 + w * 16 + lr;  // this lane's q-row (QK col i / p row)

  // ---- zero tiles (j >= NT*64) FIRST, 256B-contiguous runs per instruction:
  // 16 lanes x 16B cover one row's 64-col tile; 16 rows per instruction ----
  {
    const int zrow = tid >> 4;           // 0..15
    const int zcol = (tid & 15) * 4;     // 16 lanes x f32x4 = 256B run
    const f32x4 z = {0.f, 0.f, 0.f, 0.f};
    for (int zt = NT; zt < S / 64; ++zt) {
#pragma unroll
      for (int rg = 0; rg < 4; ++rg) {
        __builtin_nontemporal_store(
            z, (f32x4*)(a_base + (size_t)(qrow0 + rg * 16 + zrow) * S + zt * 64 + zcol));
      }
    }
  }

  // ---- Q B-fragment (col i = lr-row of this wave, k = d), QSCALE folded ----
  bf16x8 qf[2];
#pragma unroll
  for (int kh = 0; kh < 2; ++kh) {
    const float* qp = qg + bh_off + (size_t)igl * D + kh * 32 + lg * 8;
    f32x4 x0 = *(const f32x4*)(qp);
    f32x4 x1 = *(const f32x4*)(qp + 4);
    bf16x8 f;
#pragma unroll
    for (int e = 0; e < 4; ++e) {
      f[e] = f2bf(x0[e] * QSCALE);
      f[e + 4] = f2bf(x1[e] * QSCALE);
    }
    qf[kh] = f;
  }

  const int krow = tid >> 2, kc = (tid & 3) * 16;
  const int kswz = (krow & 7) << 3;
  const int vj = tid & 63, vd0 = (tid >> 6) * 16;

  // =========================== loop A: l + O(unnormalized) ===========================
  f32x4 ka[4], va[4];
  {
    const float* kp = kg + bh_off + (size_t)krow * D + kc;
#pragma unroll
    for (int i = 0; i < 4; ++i) ka[i] = *(const f32x4*)(kp + i * 4);
    const float* vp = vg + bh_off + (size_t)vj * D + vd0;
#pragma unroll
    for (int i = 0; i < 4; ++i) va[i] = *(const f32x4*)(vp + i * 4);
  }
  {  // stage tile 0
    bf16x8 kb;
#pragma unroll
    for (int e = 0; e < 4; ++e) { kb[e] = f2bf(ka[0][e]); kb[e + 4] = f2bf(ka[1][e]); }
    *(bf16x8*)(&kbuf[0][(krow * 64 + kc) ^ kswz]) = kb;
#pragma unroll
    for (int e = 0; e < 4; ++e) { kb[e] = f2bf(ka[2][e]); kb[e + 4] = f2bf(ka[3][e]); }
    *(bf16x8*)(&kbuf[0][(krow * 64 + kc + 8) ^ kswz]) = kb;
#pragma unroll
    for (int i = 0; i < 4; ++i)
#pragma unroll
      for (int e = 0; e < 4; ++e) {
        const int d = vd0 + i * 4 + e;
        vbuf[0][(d * 64 + vj) ^ ((d & 7) << 3)] = f2bf(va[i][e]);
      }
  }
  bar_lds();

  float l_acc = 0.f;
  f32x4 oacc[4];
#pragma unroll
  for (int dg = 0; dg < 4; ++dg) oacc[dg] = (f32x4){0.f, 0.f, 0.f, 0.f};

  for (int kt = 0; kt < NT; ++kt) {
    const int cur = kt & 1;
    if (kt + 1 < NT) {  // prefetch next K/V tiles into regs
      const float* kp = kg + bh_off + (size_t)((kt + 1) * 64 + krow) * D + kc;
#pragma unroll
      for (int i = 0; i < 4; ++i) ka[i] = *(const f32x4*)(kp + i * 4);
      const float* vp = vg + bh_off + (size_t)((kt + 1) * 64 + vj) * D + vd0;
#pragma unroll
      for (int i = 0; i < 4; ++i) va[i] = *(const f32x4*)(vp + i * 4);
    }

    // QK^T: D[j][i], lane col i = lr, rows j = jb*16 + lg*4 + r
    f32x4 sacc[4];
#pragma unroll
    for (int jb = 0; jb < 4; ++jb) sacc[jb] = (f32x4){0.f, 0.f, 0.f, 0.f};
#pragma unroll
    for (int kh = 0; kh < 2; ++kh) {
#pragma unroll
      for (int jb = 0; jb < 4; ++jb) {
        bf16x8 kf = *(const bf16x8*)(&kbuf[cur][((jb * 16 + lr) * 64 + kh * 32 + lg * 8) ^ asw]);
        sacc[jb] = __builtin_amdgcn_mfma_f32_16x16x32_bf16(kf, qf[kh], sacc[jb], 0, 0, 0);
      }
    }

    // p~ = exp2(s) (masked on diagonal tile); accumulate l; pscr for PV
    const bool diag = (kt == NT - 1);
#pragma unroll
    for (int jb = 0; jb < 4; ++jb) {
      short4 ps;
#pragma unroll
      for (int r = 0; r < 4; ++r) {
        const int jgl = kt * 64 + jb * 16 + lg * 4 + r;
        float pt = exp2_fast(sacc[jb][r]);
        if (diag && jgl > igl) pt = 0.f;
        l_acc += pt;
        ((short*)&ps)[r] = f2bf(pt);
      }
      *(short4*)(&pscr[w][(lr * 64 + jb * 16 + lg * 4) ^ asw]) = ps;
    }

    // PV: O[i][d] += p~ V (pscr same-wave)
#pragma unroll
    for (int ks = 0; ks < 2; ++ks) {
      bf16x8 pa = *(const bf16x8*)(&pscr[w][(lr * 64 + ks * 32 + lg * 8) ^ asw]);
#pragma unroll
      for (int dg = 0; dg < 4; ++dg) {
        bf16x8 vb = *(const bf16x8*)(&vbuf[cur][((dg * 16 + lr) * 64 + ks * 32 + lg * 8) ^ asw]);
        oacc[dg] = __builtin_amdgcn_mfma_f32_16x16x32_bf16(pa, vb, oacc[dg], 0, 0, 0);
      }
    }

    if (kt + 1 < NT) {  // stage next tile into the other buffers
      bf16x8 kb;
#pragma unroll
      for (int e = 0; e < 4; ++e) { kb[e] = f2bf(ka[0][e]); kb[e + 4] = f2bf(ka[1][e]); }
      *(bf16x8*)(&kbuf[cur ^ 1][(krow * 64 + kc) ^ kswz]) = kb;
#pragma unroll
      for (int e = 0; e < 4; ++e) { kb[e] = f2bf(ka[2][e]); kb[e + 4] = f2bf(ka[3][e]); }
      *(bf16x8*)(&kbuf[cur ^ 1][(krow * 64 + kc + 8) ^ kswz]) = kb;
#pragma unroll
      for (int i = 0; i < 4; ++i)
#pragma unroll
        for (int e = 0; e < 4; ++e) {
          const int d = vd0 + i * 4 + e;
          vbuf[cur ^ 1][(d * 64 + vj) ^ ((d & 7) << 3)] = f2bf(va[i][e]);
        }
    }
    bar_lds();
  }

  // ---- rl: reduce partials across lg; lane then holds rl for its row igl ----
  l_acc += __shfl_xor(l_acc, 16, 64);
  l_acc += __shfl_xor(l_acc, 32, 64);
  const float rlA = 1.f / l_acc;

  // O rescale needs rl at rows w*16+lg*4+r: bounce via per-wave pscr region
  {
    float* const rlv = (float*)(&pscr[w][0]);
    if (lane < 16) rlv[lr] = rlA;
    asm volatile("s_waitcnt lgkmcnt(0)" ::: "memory");  // same-wave write->read
#pragma unroll
    for (int dg = 0; dg < 4; ++dg) {
#pragma unroll
      for (int r = 0; r < 4; ++r) {
        const int il = qrow0 + w * 16 + lg * 4 + r;
        og[bh_off + (size_t)il * D + dg * 16 + lr] = oacc[dg][r] * rlv[lg * 4 + r];
      }
    }
  }

  // =========================== loop B: stream normalized a ===========================
  float* const arow = a_base + (size_t)igl * S;
  {
    const float* kp = kg + bh_off + (size_t)krow * D + kc;
#pragma unroll
    for (int i = 0; i < 4; ++i) ka[i] = *(const f32x4*)(kp + i * 4);
  }
  {  // stage tile 0 (A-loop reads of kbuf[0] finished at A's last barrier)
    bf16x8 kb;
#pragma unroll
    for (int e = 0; e < 4; ++e) { kb[e] = f2bf(ka[0][e]); kb[e + 4] = f2bf(ka[1][e]); }
    *(bf16x8*)(&kbuf[0][(krow * 64 + kc) ^ kswz]) = kb;
#pragma unroll
    for (int e = 0; e < 4; ++e) { kb[e] = f2bf(ka[2][e]); kb[e + 4] = f2bf(ka[3][e]); }
    *(bf16x8*)(&kbuf[0][(krow * 64 + kc + 8) ^ kswz]) = kb;
  }
  bar_lds();

  for (int kt = 0; kt < NT; ++kt) {
    const int cur = kt & 1;
    if (kt + 1 < NT) {  // prefetch next K tile (issued BEFORE this tile's stores)
      const float* kp = kg + bh_off + (size_t)((kt + 1) * 64 + krow) * D + kc;
#pragma unroll
      for (int i = 0; i < 4; ++i) ka[i] = *(const f32x4*)(kp + i * 4);
    }

    f32x4 sacc[4];
#pragma unroll
    for (int jb = 0; jb < 4; ++jb) sacc[jb] = (f32x4){0.f, 0.f, 0.f, 0.f};
#pragma unroll
    for (int kh = 0; kh < 2; ++kh) {
#pragma unroll
      for (int jb = 0; jb < 4; ++jb) {
        bf16x8 kf = *(const bf16x8*)(&kbuf[cur][((jb * 16 + lr) * 64 + kh * 32 + lg * 8) ^ asw]);
        sacc[jb] = __builtin_amdgcn_mfma_f32_16x16x32_bf16(kf, qf[kh], sacc[jb], 0, 0, 0);
      }
    }

    const bool diag = (kt == NT - 1);
#pragma unroll
    for (int jb = 0; jb < 4; ++jb) {
      f32x4 av;
#pragma unroll
      for (int r = 0; r < 4; ++r) {
        const int jgl = kt * 64 + jb * 16 + lg * 4 + r;
        float pt = exp2_fast(sacc[jb][r]);
        if (diag && jgl > igl) pt = 0.f;
        av[r] = pt * rlA;
      }
      __builtin_nontemporal_store(av, (f32x4*)(arow + kt * 64 + jb * 16 + lg * 4));
    }

    if (kt + 1 < NT) {
      bf16x8 kb;
#pragma unroll
      for (int e = 0; e < 4; ++e) { kb[e] = f2bf(ka[0][e]); kb[e + 4] = f2bf(ka[1][e]); }
      *(bf16x8*)(&kbuf[cur ^ 1][(krow * 64 + kc) ^ kswz]) = kb;
#pragma unroll
      for (int e = 0; e < 4; ++e) { kb[e] = f2bf(ka[2][e]); kb[e + 4] = f2bf(ka[3][e]); }
      *(bf16x8*)(&kbuf[cur ^ 1][(krow * 64 + kc + 8) ^ kswz]) = kb;
    }
    bar_lds();
  }
}

extern "C" void kernel_launch(void* const* d_in, const int* in_sizes, int n_in,
                              void* d_out, int out_size, void* d_ws, size_t ws_size,
                              hipStream_t stream) {
  const float* q = (const float*)d_in[0];
  const float* k = (const float*)d_in[1];
  const float* v = (const float*)d_in[2];
  float* out = (float*)d_out;
  attn_fused<<<dim3(2048), dim3(256), 0, stream>>>(q, k, v, out);
}

// Round 19
// 268.706 us; speedup vs baseline: 3.5031x; 1.1113x over previous
//
#include <hip/hip_runtime.h>
#include <hip/hip_bf16.h>

namespace {
constexpr int S = 2048;
constexpr int D = 64;
constexpr float QSCALE = 0.18033688011112042f;  // (1/sqrt(64)) * log2(e)

using f32x4 = __attribute__((ext_vector_type(4))) float;
using bf16x8 = __attribute__((ext_vector_type(8))) short;

__device__ __forceinline__ short f2bf(float f) {
  return __builtin_bit_cast(short, __float2bfloat16(f));  // native RNE cvt
}
__device__ __forceinline__ float bf2f(unsigned short s) {
  return __builtin_bit_cast(float, (unsigned)s << 16);
}
#if __has_builtin(__builtin_amdgcn_exp2f)
__device__ __forceinline__ float exp2_fast(float x) { return __builtin_amdgcn_exp2f(x); }
#else
__device__ __forceinline__ float exp2_fast(float x) { return exp2f(x); }
#endif

__device__ __forceinline__ void bar_lds() {  // lgkm-only barrier: vmem prefetch stays in flight
  asm volatile("s_waitcnt lgkmcnt(0)" ::: "memory");
  __builtin_amdgcn_s_barrier();
}
}  // namespace

// r18 (298.6 us) + loop-B store contiguity: normalized-a goes through the
// per-wave pscr tile (bf16) and is NT-stored as 256B-contiguous runs
// (4 rows x full 64-col tile per instruction) instead of 64B scatter.
// 40KB LDS -> 4 blocks/CU.
__global__ __launch_bounds__(256, 4) void attn_fused(const float* __restrict__ qg,
                                                     const float* __restrict__ kg,
                                                     const float* __restrict__ vg,
                                                     float* __restrict__ outg) {
  __shared__ short kbuf[2][64 * 64];   // K[j][d] bf16, XOR-swizzled, dbuf
  __shared__ short vbuf[2][64 * 64];   // V^T[d][j] bf16, XOR-swizzled, dbuf
  __shared__ short pscr[4][16 * 64];   // per-wave p~ redistribution scratch

  const int tid = threadIdx.x;
  const int w = tid >> 6, lane = tid & 63, lg = lane >> 4, lr = lane & 15;

  // XCD-chunked block map + long/short qt interleave for co-resident balance
  const int u = blockIdx.x;
  const int logical = (u & 7) * 256 + (u >> 3);  // 2048 % 8 == 0
  const int bh = logical >> 5;
  const int uu = logical & 31;
  const int qt = (uu & 1) ? (31 - (uu >> 1)) : (uu >> 1);
  const int qrow0 = qt * 64;
  const int NT = qt + 1;

  const size_t bh_off = (size_t)bh * S * D;
  float* const og = outg;
  float* const a_base = outg + (size_t)64 * S * D + (size_t)bh * S * S;
  const int asw = (lr & 7) << 3;

  const int igl = qrow0 + w * 16 + lr;  // this lane's q-row (QK col i / p row)

  // ---- zero tiles (j >= NT*64) FIRST, 256B-contiguous runs per instruction ----
  {
    const int zrow = tid >> 4;           // 0..15
    const int zcol = (tid & 15) * 4;     // 16 lanes x f32x4 = 256B run
    const f32x4 z = {0.f, 0.f, 0.f, 0.f};
    for (int zt = NT; zt < S / 64; ++zt) {
#pragma unroll
      for (int rg = 0; rg < 4; ++rg) {
        __builtin_nontemporal_store(
            z, (f32x4*)(a_base + (size_t)(qrow0 + rg * 16 + zrow) * S + zt * 64 + zcol));
      }
    }
  }

  // ---- Q B-fragment (col i = lr-row of this wave, k = d), QSCALE folded ----
  bf16x8 qf[2];
#pragma unroll
  for (int kh = 0; kh < 2; ++kh) {
    const float* qp = qg + bh_off + (size_t)igl * D + kh * 32 + lg * 8;
    f32x4 x0 = *(const f32x4*)(qp);
    f32x4 x1 = *(const f32x4*)(qp + 4);
    bf16x8 f;
#pragma unroll
    for (int e = 0; e < 4; ++e) {
      f[e] = f2bf(x0[e] * QSCALE);
      f[e + 4] = f2bf(x1[e] * QSCALE);
    }
    qf[kh] = f;
  }

  const int krow = tid >> 2, kc = (tid & 3) * 16;
  const int kswz = (krow & 7) << 3;
  const int vj = tid & 63, vd0 = (tid >> 6) * 16;

  // =========================== loop A: l + O(unnormalized) ===========================
  f32x4 ka[4], va[4];
  {
    const float* kp = kg + bh_off + (size_t)krow * D + kc;
#pragma unroll
    for (int i = 0; i < 4; ++i) ka[i] = *(const f32x4*)(kp + i * 4);
    const float* vp = vg + bh_off + (size_t)vj * D + vd0;
#pragma unroll
    for (int i = 0; i < 4; ++i) va[i] = *(const f32x4*)(vp + i * 4);
  }
  {  // stage tile 0
    bf16x8 kb;
#pragma unroll
    for (int e = 0; e < 4; ++e) { kb[e] = f2bf(ka[0][e]); kb[e + 4] = f2bf(ka[1][e]); }
    *(bf16x8*)(&kbuf[0][(krow * 64 + kc) ^ kswz]) = kb;
#pragma unroll
    for (int e = 0; e < 4; ++e) { kb[e] = f2bf(ka[2][e]); kb[e + 4] = f2bf(ka[3][e]); }
    *(bf16x8*)(&kbuf[0][(krow * 64 + kc + 8) ^ kswz]) = kb;
#pragma unroll
    for (int i = 0; i < 4; ++i)
#pragma unroll
      for (int e = 0; e < 4; ++e) {
        const int d = vd0 + i * 4 + e;
        vbuf[0][(d * 64 + vj) ^ ((d & 7) << 3)] = f2bf(va[i][e]);
      }
  }
  bar_lds();

  float l_acc = 0.f;
  f32x4 oacc[4];
#pragma unroll
  for (int dg = 0; dg < 4; ++dg) oacc[dg] = (f32x4){0.f, 0.f, 0.f, 0.f};

  for (int kt = 0; kt < NT; ++kt) {
    const int cur = kt & 1;
    if (kt + 1 < NT) {  // prefetch next K/V tiles into regs
      const float* kp = kg + bh_off + (size_t)((kt + 1) * 64 + krow) * D + kc;
#pragma unroll
      for (int i = 0; i < 4; ++i) ka[i] = *(const f32x4*)(kp + i * 4);
      const float* vp = vg + bh_off + (size_t)((kt + 1) * 64 + vj) * D + vd0;
#pragma unroll
      for (int i = 0; i < 4; ++i) va[i] = *(const f32x4*)(vp + i * 4);
    }

    // QK^T: D[j][i], lane col i = lr, rows j = jb*16 + lg*4 + r
    f32x4 sacc[4];
#pragma unroll
    for (int jb = 0; jb < 4; ++jb) sacc[jb] = (f32x4){0.f, 0.f, 0.f, 0.f};
#pragma unroll
    for (int kh = 0; kh < 2; ++kh) {
#pragma unroll
      for (int jb = 0; jb < 4; ++jb) {
        bf16x8 kf = *(const bf16x8*)(&kbuf[cur][((jb * 16 + lr) * 64 + kh * 32 + lg * 8) ^ asw]);
        sacc[jb] = __builtin_amdgcn_mfma_f32_16x16x32_bf16(kf, qf[kh], sacc[jb], 0, 0, 0);
      }
    }

    // p~ = exp2(s) (masked on diagonal tile); accumulate l; pscr for PV
    const bool diag = (kt == NT - 1);
#pragma unroll
    for (int jb = 0; jb < 4; ++jb) {
      short4 ps;
#pragma unroll
      for (int r = 0; r < 4; ++r) {
        const int jgl = kt * 64 + jb * 16 + lg * 4 + r;
        float pt = exp2_fast(sacc[jb][r]);
        if (diag && jgl > igl) pt = 0.f;
        l_acc += pt;
        ((short*)&ps)[r] = f2bf(pt);
      }
      *(short4*)(&pscr[w][(lr * 64 + jb * 16 + lg * 4) ^ asw]) = ps;
    }

    // PV: O[i][d] += p~ V (pscr same-wave)
#pragma unroll
    for (int ks = 0; ks < 2; ++ks) {
      bf16x8 pa = *(const bf16x8*)(&pscr[w][(lr * 64 + ks * 32 + lg * 8) ^ asw]);
#pragma unroll
      for (int dg = 0; dg < 4; ++dg) {
        bf16x8 vb = *(const bf16x8*)(&vbuf[cur][((dg * 16 + lr) * 64 + ks * 32 + lg * 8) ^ asw]);
        oacc[dg] = __builtin_amdgcn_mfma_f32_16x16x32_bf16(pa, vb, oacc[dg], 0, 0, 0);
      }
    }

    if (kt + 1 < NT) {  // stage next tile into the other buffers
      bf16x8 kb;
#pragma unroll
      for (int e = 0; e < 4; ++e) { kb[e] = f2bf(ka[0][e]); kb[e + 4] = f2bf(ka[1][e]); }
      *(bf16x8*)(&kbuf[cur ^ 1][(krow * 64 + kc) ^ kswz]) = kb;
#pragma unroll
      for (int e = 0; e < 4; ++e) { kb[e] = f2bf(ka[2][e]); kb[e + 4] = f2bf(ka[3][e]); }
      *(bf16x8*)(&kbuf[cur ^ 1][(krow * 64 + kc + 8) ^ kswz]) = kb;
#pragma unroll
      for (int i = 0; i < 4; ++i)
#pragma unroll
        for (int e = 0; e < 4; ++e) {
          const int d = vd0 + i * 4 + e;
          vbuf[cur ^ 1][(d * 64 + vj) ^ ((d & 7) << 3)] = f2bf(va[i][e]);
        }
    }
    bar_lds();
  }

  // ---- rl: reduce partials across lg; lane then holds rl for its row igl ----
  l_acc += __shfl_xor(l_acc, 16, 64);
  l_acc += __shfl_xor(l_acc, 32, 64);
  const float rlA = 1.f / l_acc;

  // O rescale needs rl at rows w*16+lg*4+r: bounce via per-wave pscr region
  {
    float* const rlv = (float*)(&pscr[w][0]);
    if (lane < 16) rlv[lr] = rlA;
    asm volatile("s_waitcnt lgkmcnt(0)" ::: "memory");  // same-wave write->read
#pragma unroll
    for (int dg = 0; dg < 4; ++dg) {
#pragma unroll
      for (int r = 0; r < 4; ++r) {
        const int il = qrow0 + w * 16 + lg * 4 + r;
        og[bh_off + (size_t)il * D + dg * 16 + lr] = oacc[dg][r] * rlv[lg * 4 + r];
      }
    }
  }

  // ====== loop B: normalized a via pscr transpose -> 256B-contiguous NT stores ======
  {
    const float* kp = kg + bh_off + (size_t)krow * D + kc;
#pragma unroll
    for (int i = 0; i < 4; ++i) ka[i] = *(const f32x4*)(kp + i * 4);
  }
  {  // stage tile 0 (A-loop reads of kbuf[0] finished at A's last barrier)
    bf16x8 kb;
#pragma unroll
    for (int e = 0; e < 4; ++e) { kb[e] = f2bf(ka[0][e]); kb[e + 4] = f2bf(ka[1][e]); }
    *(bf16x8*)(&kbuf[0][(krow * 64 + kc) ^ kswz]) = kb;
#pragma unroll
    for (int e = 0; e < 4; ++e) { kb[e] = f2bf(ka[2][e]); kb[e + 4] = f2bf(ka[3][e]); }
    *(bf16x8*)(&kbuf[0][(krow * 64 + kc + 8) ^ kswz]) = kb;
  }
  bar_lds();

  const int i2 = (lane >> 4);        // row-subgroup for the store phase
  const int c2 = (lane & 15) * 4;    // 16 lanes x f32x4 = full 64-col tile row
  for (int kt = 0; kt < NT; ++kt) {
    const int cur = kt & 1;
    if (kt + 1 < NT) {  // prefetch next K tile (issued BEFORE this tile's stores)
      const float* kp = kg + bh_off + (size_t)((kt + 1) * 64 + krow) * D + kc;
#pragma unroll
      for (int i = 0; i < 4; ++i) ka[i] = *(const f32x4*)(kp + i * 4);
    }

    f32x4 sacc[4];
#pragma unroll
    for (int jb = 0; jb < 4; ++jb) sacc[jb] = (f32x4){0.f, 0.f, 0.f, 0.f};
#pragma unroll
    for (int kh = 0; kh < 2; ++kh) {
#pragma unroll
      for (int jb = 0; jb < 4; ++jb) {
        bf16x8 kf = *(const bf16x8*)(&kbuf[cur][((jb * 16 + lr) * 64 + kh * 32 + lg * 8) ^ asw]);
        sacc[jb] = __builtin_amdgcn_mfma_f32_16x16x32_bf16(kf, qf[kh], sacc[jb], 0, 0, 0);
      }
    }

    // p~*rl -> bf16 -> pscr (lane's row lr is its own: rlA correct)
    const bool diag = (kt == NT - 1);
#pragma unroll
    for (int jb = 0; jb < 4; ++jb) {
      short4 ps;
#pragma unroll
      for (int r = 0; r < 4; ++r) {
        const int jgl = kt * 64 + jb * 16 + lg * 4 + r;
        float pt = exp2_fast(sacc[jb][r]);
        if (diag && jgl > igl) pt = 0.f;
        ((short*)&ps)[r] = f2bf(pt * rlA);
      }
      *(short4*)(&pscr[w][(lr * 64 + jb * 16 + lg * 4) ^ asw]) = ps;
    }

    // transpose-read + NT store: one instruction = 4 rows x 256B-contiguous runs
#pragma unroll
    for (int it = 0; it < 4; ++it) {
      const int row = it * 4 + i2;
      short4 pv4 = *(const short4*)(&pscr[w][(row * 64 + c2) ^ ((row & 7) << 3)]);
      f32x4 av = {bf2f((unsigned short)pv4.x), bf2f((unsigned short)pv4.y),
                  bf2f((unsigned short)pv4.z), bf2f((unsigned short)pv4.w)};
      __builtin_nontemporal_store(
          av, (f32x4*)(a_base + (size_t)(qrow0 + w * 16 + row) * S + kt * 64 + c2));
    }

    if (kt + 1 < NT) {
      bf16x8 kb;
#pragma unroll
      for (int e = 0; e < 4; ++e) { kb[e] = f2bf(ka[0][e]); kb[e + 4] = f2bf(ka[1][e]); }
      *(bf16x8*)(&kbuf[cur ^ 1][(krow * 64 + kc) ^ kswz]) = kb;
#pragma unroll
      for (int e = 0; e < 4; ++e) { kb[e] = f2bf(ka[2][e]); kb[e + 4] = f2bf(ka[3][e]); }
      *(bf16x8*)(&kbuf[cur ^ 1][(krow * 64 + kc + 8) ^ kswz]) = kb;
    }
    bar_lds();
  }
}

extern "C" void kernel_launch(void* const* d_in, const int* in_sizes, int n_in,
                              void* d_out, int out_size, void* d_ws, size_t ws_size,
                              hipStream_t stream) {
  const float* q = (const float*)d_in[0];
  const float* k = (const float*)d_in[1];
  const float* v = (const float*)d_in[2];
  float* out = (float*)d_out;
  attn_fused<<<dim3(2048), dim3(256), 0, stream>>>(q, k, v, out);
}